// Round 1
// baseline (581.867 us; speedup 1.0000x reference)
//
#include <hip/hip_runtime.h>
#include <hip/hip_bf16.h>
#include <cstdint>
#include <cstddef>

#define S 2048
#define D 4096
#define H 32
#define G 8
#define DH 128
#define HD (H*DH)   // 4096
#define GD (G*DH)   // 1024

typedef __bf16 bf16;
typedef __bf16 bf16x4 __attribute__((ext_vector_type(4)));
typedef __bf16 bf16x8 __attribute__((ext_vector_type(8)));
typedef float f32x4 __attribute__((ext_vector_type(4)));

// ---------------------------------------------------------------- cast x -> bf16
__global__ __launch_bounds__(256) void cast_f32_bf16(const float* __restrict__ in,
                                                     bf16* __restrict__ out, int n4)
{
    int i = blockIdx.x * 256 + threadIdx.x;
    if (i < n4) {
        float4 v = reinterpret_cast<const float4*>(in)[i];
        bf16x4 o = { (bf16)v.x, (bf16)v.y, (bf16)v.z, (bf16)v.w };
        reinterpret_cast<bf16x4*>(out)[i] = o;
    }
}

// ---------------------------------------------------------------- RoPE in-place
// one thread owns the (d, d+64) pair of one head-row -> race-free in-place.
// cos[s, d] == cos[s, d+64] (emb = concat([freqs,freqs])).
__global__ __launch_bounds__(256) void rope_inplace(bf16* __restrict__ Y,
                                                    const float* __restrict__ cosT,
                                                    const float* __restrict__ sinT,
                                                    int ncols, int total)
{
    int idx = blockIdx.x * 256 + threadIdx.x;
    if (idx >= total) return;
    int pairs = ncols >> 1;
    int s = idx / pairs;
    int p = idx - s * pairs;
    int head = p >> 6;
    int d = p & 63;
    size_t base = (size_t)s * ncols + head * DH;
    float c  = cosT[s * DH + d];
    float sn = sinT[s * DH + d];
    float a = (float)Y[base + d];
    float b = (float)Y[base + d + 64];
    Y[base + d]      = (bf16)(a * c - b * sn);
    Y[base + d + 64] = (bf16)(b * c + a * sn);
}

// ---------------------------------------------------------------- GEMM
// C[M,N] = A[M,K](bf16) * B[K,N](fp32, converted to bf16 during LDS staging)
// 128x128 tile, BK=32, 256 threads (4 waves, each 64x64).
// B staged transposed (Bt[n][k]) so b-frags are contiguous ds_read_b128.
// blockIdx.z selects (B0,C0)/(B1,C1) so K and V projections share one launch.
#define BM 128
#define BN 128
#define BK 32
#define LDSK 40   // +8 bf16 pad -> row stride 80B = 20 dw -> 2-way conflicts (free)

template<bool OUT_BF16>
__global__ __launch_bounds__(256) void gemm_aBf16(
    const bf16* __restrict__ A,
    const float* __restrict__ B0, const float* __restrict__ B1,
    void* __restrict__ C0, void* __restrict__ C1,
    int M, int N, int K)
{
    __shared__ alignas(16) bf16 Al[BM][LDSK];
    __shared__ alignas(16) bf16 Bt[BN][LDSK];

    const float* __restrict__ B = blockIdx.z ? B1 : B0;
    void* __restrict__ C = blockIdx.z ? C1 : C0;

    const int tid  = threadIdx.x;
    const int lane = tid & 63;
    const int wave = tid >> 6;
    const int wm = (wave >> 1) * 64;
    const int wn = (wave & 1) * 64;
    const int bm = blockIdx.y * BM;
    const int bn = blockIdx.x * BN;
    const int l15 = lane & 15;
    const int lhi = lane >> 4;

    f32x4 acc[4][4] = {};

    for (int k0 = 0; k0 < K; k0 += BK) {
        // stage A tile [128][32] bf16: 2 x b128 per thread
        #pragma unroll
        for (int it = 0; it < 2; ++it) {
            int idx = it * 256 + tid;
            int row = idx >> 2;
            int ko  = idx & 3;
            bf16x8 v = *reinterpret_cast<const bf16x8*>(
                A + (size_t)(bm + row) * K + k0 + ko * 8);
            *reinterpret_cast<bf16x8*>(&Al[row][ko * 8]) = v;
        }
        // stage B tile transposed: Bt[n][k]; coalesced fp32 row reads, cvt to bf16
        {
            int n = tid & 127;
            int kbase = (tid >> 7) * 8;   // 0 or 8
            const float* bp = B + (size_t)k0 * N + bn + n;
            #pragma unroll
            for (int half = 0; half < 2; ++half) {
                bf16x8 v;
                #pragma unroll
                for (int j = 0; j < 8; ++j)
                    v[j] = (bf16)bp[(size_t)(half * 16 + kbase + j) * N];
                *reinterpret_cast<bf16x8*>(&Bt[n][half * 16 + kbase]) = v;
            }
        }
        __syncthreads();

        bf16x8 af[4], bfv[4];
        #pragma unroll
        for (int m = 0; m < 4; ++m)
            af[m] = *reinterpret_cast<const bf16x8*>(&Al[wm + m * 16 + l15][lhi * 8]);
        #pragma unroll
        for (int n = 0; n < 4; ++n)
            bfv[n] = *reinterpret_cast<const bf16x8*>(&Bt[wn + n * 16 + l15][lhi * 8]);
        #pragma unroll
        for (int m = 0; m < 4; ++m)
            #pragma unroll
            for (int n = 0; n < 4; ++n)
                acc[m][n] = __builtin_amdgcn_mfma_f32_16x16x32_bf16(
                    af[m], bfv[n], acc[m][n], 0, 0, 0);
        __syncthreads();
    }

    // epilogue: C/D layout col=lane&15, row=(lane>>4)*4+j
    #pragma unroll
    for (int m = 0; m < 4; ++m) {
        int r0 = bm + wm + m * 16 + lhi * 4;
        #pragma unroll
        for (int n = 0; n < 4; ++n) {
            int c = bn + wn + n * 16 + l15;
            #pragma unroll
            for (int j = 0; j < 4; ++j) {
                if constexpr (OUT_BF16)
                    reinterpret_cast<bf16*>(C)[(size_t)(r0 + j) * N + c] = (bf16)acc[m][n][j];
                else
                    reinterpret_cast<float*>(C)[(size_t)(r0 + j) * N + c] = acc[m][n][j];
            }
        }
    }
}

// ---------------------------------------------------------------- flash attention
// block = (head h, 64 q-rows). 4 waves x 16 rows. KVBLK=64.
// K LDS row-major (QK^T b-frag contiguous); V staged transposed (PV b-frag contiguous).
// online softmax per q-row via width-16 shfl_xor reductions.
#define QBLK 64
#define KVBLK 64
#define DHP 136   // 128+8 pad
#define KVP 72    // 64+8 pad

__global__ __launch_bounds__(256) void flash_fwd(
    const bf16* __restrict__ Q, const bf16* __restrict__ Kr,
    const bf16* __restrict__ Vr, bf16* __restrict__ ctx)
{
    __shared__ alignas(16) bf16 Kl[KVBLK][DHP];
    __shared__ alignas(16) bf16 Vt[DH][KVP];
    __shared__ alignas(16) bf16 Pl[4][16][KVP];

    const int tid  = threadIdx.x;
    const int lane = tid & 63;
    const int wave = tid >> 6;
    const int l15 = lane & 15;
    const int lhi = lane >> 4;
    const int qt = blockIdx.x;
    const int h  = blockIdx.y;
    const int g  = h >> 2;          // GROUP = 4
    const int q0 = qt * QBLK;

    // Q fragments straight from global (per wave: 16 rows x 128 k)
    bf16x8 qf[4];
    {
        const bf16* qp = Q + (size_t)(q0 + wave * 16 + l15) * HD + h * DH + lhi * 8;
        #pragma unroll
        for (int kk = 0; kk < 4; ++kk)
            qf[kk] = *reinterpret_cast<const bf16x8*>(qp + kk * 32);
    }

    f32x4 o[8] = {};
    float m_i[4] = { -1e30f, -1e30f, -1e30f, -1e30f };
    float l_i[4] = {};
    const float scale = 0.08838834764831845f;  // 1/sqrt(128)

    for (int t0 = 0; t0 <= q0; t0 += KVBLK) {
        // stage K tile [64][128]
        #pragma unroll
        for (int it = 0; it < 4; ++it) {
            int idx = it * 256 + tid;
            int row = idx >> 4;
            int co  = idx & 15;
            *reinterpret_cast<bf16x8*>(&Kl[row][co * 8]) =
                *reinterpret_cast<const bf16x8*>(
                    Kr + (size_t)(t0 + row) * GD + g * DH + co * 8);
        }
        // stage V transposed: Vt[d][kv]
        {
            int d   = tid & 127;
            int kv0 = (tid >> 7) * 8;
            #pragma unroll
            for (int half = 0; half < 4; ++half) {
                int kvb = half * 16 + kv0;
                bf16x8 v;
                #pragma unroll
                for (int j = 0; j < 8; ++j)
                    v[j] = Vr[(size_t)(t0 + kvb + j) * GD + g * DH + d];
                *reinterpret_cast<bf16x8*>(&Vt[d][kvb]) = v;
            }
        }
        __syncthreads();

        // QK^T: per wave 16 x 64 scores
        f32x4 sc[4] = {};
        #pragma unroll
        for (int n = 0; n < 4; ++n)
            #pragma unroll
            for (int kk = 0; kk < 4; ++kk) {
                bf16x8 kf = *reinterpret_cast<const bf16x8*>(
                    &Kl[n * 16 + l15][kk * 32 + lhi * 8]);
                sc[n] = __builtin_amdgcn_mfma_f32_16x16x32_bf16(qf[kk], kf, sc[n], 0, 0, 0);
            }

        // online softmax (row = (lhi*4+j), col = n*16+l15)
        float pv[4][4];
        float corr[4];
        #pragma unroll
        for (int j = 0; j < 4; ++j) {
            int qr = q0 + wave * 16 + lhi * 4 + j;
            float vals[4];
            float mx = -1e30f;
            #pragma unroll
            for (int n = 0; n < 4; ++n) {
                int t = t0 + n * 16 + l15;
                float val = (t <= qr) ? sc[n][j] * scale : -1e30f;
                vals[n] = val;
                mx = fmaxf(mx, val);
            }
            #pragma unroll
            for (int ms = 1; ms < 16; ms <<= 1)
                mx = fmaxf(mx, __shfl_xor(mx, ms, 16));
            float mnew = fmaxf(m_i[j], mx);
            float cr = __expf(m_i[j] - mnew);
            float rsum = 0.f;
            #pragma unroll
            for (int n = 0; n < 4; ++n) {
                float p = __expf(vals[n] - mnew);
                pv[j][n] = p;
                rsum += p;
            }
            #pragma unroll
            for (int ms = 1; ms < 16; ms <<= 1)
                rsum += __shfl_xor(rsum, ms, 16);
            l_i[j] = l_i[j] * cr + rsum;
            m_i[j] = mnew;
            corr[j] = cr;
        }

        // rescale running O
        #pragma unroll
        for (int n = 0; n < 8; ++n)
            #pragma unroll
            for (int j = 0; j < 4; ++j)
                o[n][j] *= corr[j];

        // P -> LDS (bf16), then PV
        #pragma unroll
        for (int j = 0; j < 4; ++j)
            #pragma unroll
            for (int n = 0; n < 4; ++n)
                Pl[wave][lhi * 4 + j][n * 16 + l15] = (bf16)pv[j][n];
        __syncthreads();

        #pragma unroll
        for (int kk = 0; kk < 2; ++kk) {
            bf16x8 pf = *reinterpret_cast<const bf16x8*>(
                &Pl[wave][l15][kk * 32 + lhi * 8]);
            #pragma unroll
            for (int n = 0; n < 8; ++n) {
                bf16x8 vf = *reinterpret_cast<const bf16x8*>(
                    &Vt[n * 16 + l15][kk * 32 + lhi * 8]);
                o[n] = __builtin_amdgcn_mfma_f32_16x16x32_bf16(pf, vf, o[n], 0, 0, 0);
            }
        }
        __syncthreads();   // protect Kl/Vt before next stage
    }

    // normalize + write ctx [S][H*DH]
    #pragma unroll
    for (int n = 0; n < 8; ++n) {
        int c = h * DH + n * 16 + l15;
        #pragma unroll
        for (int j = 0; j < 4; ++j) {
            int r = q0 + wave * 16 + lhi * 4 + j;
            ctx[(size_t)r * HD + c] = (bf16)(o[n][j] / l_i[j]);
        }
    }
}

// ---------------------------------------------------------------- launch
extern "C" void kernel_launch(void* const* d_in, const int* in_sizes, int n_in,
                              void* d_out, int out_size, void* d_ws, size_t ws_size,
                              hipStream_t stream)
{
    const float* x    = (const float*)d_in[0];
    // d_in[1] = causal mask, known analytically -> ignored
    const float* cosT = (const float*)d_in[2];
    const float* sinT = (const float*)d_in[3];
    const float* Wq   = (const float*)d_in[4];
    const float* Wk   = (const float*)d_in[5];
    const float* Wv   = (const float*)d_in[6];
    const float* Wo   = (const float*)d_in[7];
    float* out = (float*)d_out;

    // workspace: xb (16MB) | ctx (16MB).  Q/K/V (24MB bf16) live in d_out (32MB fp32),
    // which is dead until the final GEMM overwrites it.
    char* ws  = (char*)d_ws;
    bf16* xb  = (bf16*)ws;                          // S*D bf16        = 16MB
    bf16* ctx = (bf16*)(ws + ((size_t)16 << 20));   // S*HD bf16       = 16MB
    bf16* Qb  = (bf16*)d_out;                       // S*HD bf16       = 16MB
    bf16* Kb  = Qb + (size_t)S * HD;                // S*GD bf16       =  4MB
    bf16* Vb  = Kb + (size_t)S * GD;                // S*GD bf16       =  4MB

    cast_f32_bf16<<<(S * D / 4 + 255) / 256, 256, 0, stream>>>(x, xb, S * D / 4);

    // Q = x@Wq ; {K,V} = x@{Wk,Wv} fused via gridDim.z
    gemm_aBf16<true><<<dim3(HD / BN, S / BM, 1), 256, 0, stream>>>(
        xb, Wq, Wq, (void*)Qb, (void*)Qb, S, HD, D);
    gemm_aBf16<true><<<dim3(GD / BN, S / BM, 2), 256, 0, stream>>>(
        xb, Wk, Wv, (void*)Kb, (void*)Vb, S, GD, D);

    rope_inplace<<<(S * HD / 2 + 255) / 256, 256, 0, stream>>>(Qb, cosT, sinT, HD, S * HD / 2);
    rope_inplace<<<(S * GD / 2 + 255) / 256, 256, 0, stream>>>(Kb, cosT, sinT, GD, S * GD / 2);

    flash_fwd<<<dim3(S / QBLK, H), 256, 0, stream>>>(Qb, Kb, Vb, ctx);

    gemm_aBf16<false><<<dim3(D / BN, S / BM, 1), 256, 0, stream>>>(
        ctx, Wo, Wo, (void*)out, (void*)out, S, D, HD);

    (void)in_sizes; (void)n_in; (void)out_size; (void)ws_size;
}

// Round 2
// 493.640 us; speedup vs baseline: 1.1787x; 1.1787x over previous
//
#include <hip/hip_runtime.h>
#include <hip/hip_bf16.h>
#include <cstdint>
#include <cstddef>

#define S 2048
#define D 4096
#define H 32
#define G 8
#define DH 128
#define HD (H*DH)   // 4096
#define GD (G*DH)   // 1024

typedef __bf16 bf16;
typedef __bf16 bf16x4 __attribute__((ext_vector_type(4)));
typedef __bf16 bf16x8 __attribute__((ext_vector_type(8)));
typedef float f32x4 __attribute__((ext_vector_type(4)));

__device__ __forceinline__ void gload16(const void* g, void* l) {
    __builtin_amdgcn_global_load_lds(
        (const __attribute__((address_space(1))) void*)g,
        (__attribute__((address_space(3))) void*)l, 16, 0, 0);
}

// ---------------------------------------------------------------- cast x -> bf16
__global__ __launch_bounds__(256) void cast_f32_bf16(const float* __restrict__ in,
                                                     bf16* __restrict__ out, int n4)
{
    int i = blockIdx.x * 256 + threadIdx.x;
    if (i < n4) {
        float4 v = reinterpret_cast<const float4*>(in)[i];
        bf16x4 o = { (bf16)v.x, (bf16)v.y, (bf16)v.z, (bf16)v.w };
        reinterpret_cast<bf16x4*>(out)[i] = o;
    }
}

// ---------------------------------------------------------------- transpose -> bf16
// in [R][C] (f32 or bf16) -> out [C][R] bf16.  8x8 register micro-tiles.
// block 256 = 4 (r-blocks) x 64 (c-blocks); grid (C/512, R/32).
template<bool IN_F32>
__global__ __launch_bounds__(256) void transpose_to_bf16(
    const void* __restrict__ in, bf16* __restrict__ out, int R, int C)
{
    const int cb = threadIdx.x & 63, rb = threadIdx.x >> 6;
    const int c0 = blockIdx.x * 512 + cb * 8;
    const int r0 = blockIdx.y * 32 + rb * 8;
    bf16 m[8][8];
    #pragma unroll
    for (int j = 0; j < 8; ++j) {
        if constexpr (IN_F32) {
            const float* p = (const float*)in + (size_t)(r0 + j) * C + c0;
            float4 a = *reinterpret_cast<const float4*>(p);
            float4 b = *reinterpret_cast<const float4*>(p + 4);
            m[j][0] = (bf16)a.x; m[j][1] = (bf16)a.y; m[j][2] = (bf16)a.z; m[j][3] = (bf16)a.w;
            m[j][4] = (bf16)b.x; m[j][5] = (bf16)b.y; m[j][6] = (bf16)b.z; m[j][7] = (bf16)b.w;
        } else {
            const bf16* p = (const bf16*)in + (size_t)(r0 + j) * C + c0;
            bf16x8 v = *reinterpret_cast<const bf16x8*>(p);
            #pragma unroll
            for (int i = 0; i < 8; ++i) m[j][i] = v[i];
        }
    }
    #pragma unroll
    for (int i = 0; i < 8; ++i) {
        bf16x8 ov;
        #pragma unroll
        for (int j = 0; j < 8; ++j) ov[j] = m[j][i];
        *reinterpret_cast<bf16x8*>(out + (size_t)(c0 + i) * R + r0) = ov;
    }
}

// ---------------------------------------------------------------- RoPE in-place (+scale)
__global__ __launch_bounds__(256) void rope_inplace(bf16* __restrict__ Y,
                                                    const float* __restrict__ cosT,
                                                    const float* __restrict__ sinT,
                                                    int ncols, int total, float scale)
{
    int idx = blockIdx.x * 256 + threadIdx.x;
    if (idx >= total) return;
    int pairs = ncols >> 1;
    int s = idx / pairs;
    int p = idx - s * pairs;
    int head = p >> 6;
    int d = p & 63;
    size_t base = (size_t)s * ncols + head * DH;
    float c  = cosT[s * DH + d];
    float sn = sinT[s * DH + d];
    float a = (float)Y[base + d];
    float b = (float)Y[base + d + 64];
    Y[base + d]      = (bf16)((a * c - b * sn) * scale);
    Y[base + d + 64] = (bf16)((b * c + a * sn) * scale);
}

// ---------------------------------------------------------------- fast GEMM (m97 structure)
// C[M,N] = A[M,K](bf16) * Bt[N,K](bf16).  128x128 tile, BK=32, global_load_lds both.
#define BM 128
#define BN 128
#define BK 32

#define EPI_QKV 0
#define EPI_F32 1

template<int EPI>
__global__ __launch_bounds__(256) void gemm_bt(
    const bf16* __restrict__ A, const bf16* __restrict__ Bt,
    void* __restrict__ C, bf16* __restrict__ Kout, bf16* __restrict__ Vout,
    int M, int N, int K)
{
    __shared__ alignas(16) bf16 Al[BM * BK];
    __shared__ alignas(16) bf16 Bl[BN * BK];

    const int tid  = threadIdx.x;
    const int lane = tid & 63;
    const int wave = tid >> 6;
    const int wm = (wave >> 1) * 64;
    const int wn = (wave & 1) * 64;
    const int bm = blockIdx.y * BM;
    const int bn = blockIdx.x * BN;
    const int l15 = lane & 15;
    const int lhi = lane >> 4;

    f32x4 acc[4][4] = {};

    for (int k0 = 0; k0 < K; k0 += BK) {
        #pragma unroll
        for (int t = 0; t < 2; ++t) {
            int ch  = wave * 128 + t * 64 + lane;
            int row = ch >> 2, cb = ch & 3;
            gload16(A  + (size_t)(bm + row) * K + k0 + cb * 8,
                    (char*)Al + (wave * 128 + t * 64) * 16);
            gload16(Bt + (size_t)(bn + row) * K + k0 + cb * 8,
                    (char*)Bl + (wave * 128 + t * 64) * 16);
        }
        __syncthreads();

        bf16x8 af[4], bfv[4];
        #pragma unroll
        for (int m = 0; m < 4; ++m)
            af[m] = *reinterpret_cast<const bf16x8*>(&Al[(wm + m * 16 + l15) * BK + lhi * 8]);
        #pragma unroll
        for (int n = 0; n < 4; ++n)
            bfv[n] = *reinterpret_cast<const bf16x8*>(&Bl[(wn + n * 16 + l15) * BK + lhi * 8]);
        #pragma unroll
        for (int m = 0; m < 4; ++m)
            #pragma unroll
            for (int n = 0; n < 4; ++n)
                acc[m][n] = __builtin_amdgcn_mfma_f32_16x16x32_bf16(
                    af[m], bfv[n], acc[m][n], 0, 0, 0);
        __syncthreads();
    }

    #pragma unroll
    for (int m = 0; m < 4; ++m) {
        int r0 = bm + wm + m * 16 + lhi * 4;
        #pragma unroll
        for (int n = 0; n < 4; ++n) {
            int c = bn + wn + n * 16 + l15;
            #pragma unroll
            for (int j = 0; j < 4; ++j) {
                if constexpr (EPI == EPI_F32) {
                    reinterpret_cast<float*>(C)[(size_t)(r0 + j) * N + c] = acc[m][n][j];
                } else {
                    // column-split: [0,4096)->Q, [4096,5120)->K, [5120,6144)->V (uniform per block)
                    if (bn < HD)
                        reinterpret_cast<bf16*>(C)[(size_t)(r0 + j) * HD + c] = (bf16)acc[m][n][j];
                    else if (bn < HD + GD)
                        Kout[(size_t)(r0 + j) * GD + (c - HD)] = (bf16)acc[m][n][j];
                    else
                        Vout[(size_t)(r0 + j) * GD + (c - HD - GD)] = (bf16)acc[m][n][j];
                }
            }
        }
    }
}

// ---------------------------------------------------------------- fallback GEMM (round-1)
#define LDSK 40

template<bool OUT_BF16>
__global__ __launch_bounds__(256) void gemm_aBf16(
    const bf16* __restrict__ A,
    const float* __restrict__ B0, const float* __restrict__ B1,
    void* __restrict__ C0, void* __restrict__ C1,
    int M, int N, int K)
{
    __shared__ alignas(16) bf16 Al[BM][LDSK];
    __shared__ alignas(16) bf16 Bt[BN][LDSK];

    const float* __restrict__ B = blockIdx.z ? B1 : B0;
    void* __restrict__ C = blockIdx.z ? C1 : C0;

    const int tid  = threadIdx.x;
    const int lane = tid & 63;
    const int wave = tid >> 6;
    const int wm = (wave >> 1) * 64;
    const int wn = (wave & 1) * 64;
    const int bm = blockIdx.y * BM;
    const int bn = blockIdx.x * BN;
    const int l15 = lane & 15;
    const int lhi = lane >> 4;

    f32x4 acc[4][4] = {};

    for (int k0 = 0; k0 < K; k0 += BK) {
        #pragma unroll
        for (int it = 0; it < 2; ++it) {
            int idx = it * 256 + tid;
            int row = idx >> 2;
            int ko  = idx & 3;
            bf16x8 v = *reinterpret_cast<const bf16x8*>(
                A + (size_t)(bm + row) * K + k0 + ko * 8);
            *reinterpret_cast<bf16x8*>(&Al[row][ko * 8]) = v;
        }
        {
            int n = tid & 127;
            int kbase = (tid >> 7) * 8;
            const float* bp = B + (size_t)k0 * N + bn + n;
            #pragma unroll
            for (int half = 0; half < 2; ++half) {
                bf16x8 v;
                #pragma unroll
                for (int j = 0; j < 8; ++j)
                    v[j] = (bf16)bp[(size_t)(half * 16 + kbase + j) * N];
                *reinterpret_cast<bf16x8*>(&Bt[n][half * 16 + kbase]) = v;
            }
        }
        __syncthreads();

        bf16x8 af[4], bfv[4];
        #pragma unroll
        for (int m = 0; m < 4; ++m)
            af[m] = *reinterpret_cast<const bf16x8*>(&Al[wm + m * 16 + l15][lhi * 8]);
        #pragma unroll
        for (int n = 0; n < 4; ++n)
            bfv[n] = *reinterpret_cast<const bf16x8*>(&Bt[wn + n * 16 + l15][lhi * 8]);
        #pragma unroll
        for (int m = 0; m < 4; ++m)
            #pragma unroll
            for (int n = 0; n < 4; ++n)
                acc[m][n] = __builtin_amdgcn_mfma_f32_16x16x32_bf16(
                    af[m], bfv[n], acc[m][n], 0, 0, 0);
        __syncthreads();
    }

    #pragma unroll
    for (int m = 0; m < 4; ++m) {
        int r0 = bm + wm + m * 16 + lhi * 4;
        #pragma unroll
        for (int n = 0; n < 4; ++n) {
            int c = bn + wn + n * 16 + l15;
            #pragma unroll
            for (int j = 0; j < 4; ++j) {
                if constexpr (OUT_BF16)
                    reinterpret_cast<bf16*>(C)[(size_t)(r0 + j) * N + c] = (bf16)acc[m][n][j];
                else
                    reinterpret_cast<float*>(C)[(size_t)(r0 + j) * N + c] = acc[m][n][j];
            }
        }
    }
}

// ---------------------------------------------------------------- flash attention v2
// block = (head, 64 q-rows), 4 waves x 16 rows, KVBLK=64.
// Kl: [64][128] row-major (t x d), XOR-swizzled chunks, staged via global_load_lds
//     with pre-swizzled SOURCE addresses (both-sides rule).
// Vl: [128][64] = V^T tile (d x t), same treatment; source is the globally
//     pre-transposed VtG [G*DH][S].
// Pl: per-wave [16][64] q x t, XOR-swizzled; no barrier needed (single-wave use).
#define QBLK 64
#define KVBLK 64
#define NQT (S/QBLK)

template<bool MASK>
__device__ __forceinline__ void attn_tile(
    int t0, int q0, int wave, int l15, int lhi,
    const bf16x8* qf, const bf16* Kl, const bf16* Vl, bf16* Plw,
    f32x4* o, float* m_i, float* l_i)
{
    f32x4 sc[4] = {};
    #pragma unroll
    for (int n = 0; n < 4; ++n) {
        int row = n * 16 + l15;
        #pragma unroll
        for (int kk = 0; kk < 4; ++kk) {
            bf16x8 kf = *reinterpret_cast<const bf16x8*>(
                (const char*)Kl + row * 256 + ((((kk * 4 + lhi)) ^ (l15 & 7)) << 4));
            sc[n] = __builtin_amdgcn_mfma_f32_16x16x32_bf16(qf[kk], kf, sc[n], 0, 0, 0);
        }
    }

    float corr[4];
    #pragma unroll
    for (int j = 0; j < 4; ++j) {
        const int qr = q0 + wave * 16 + lhi * 4 + j;
        float vals[4];
        float mx = -1e30f;
        #pragma unroll
        for (int n = 0; n < 4; ++n) {
            float v = sc[n][j];
            if constexpr (MASK) {
                int t = t0 + n * 16 + l15;
                if (t > qr) v = -1e30f;
            }
            vals[n] = v;
            mx = fmaxf(mx, v);
        }
        #pragma unroll
        for (int ms = 1; ms < 16; ms <<= 1)
            mx = fmaxf(mx, __shfl_xor(mx, ms, 16));
        float mnew = fmaxf(m_i[j], mx);
        float cr = __expf(m_i[j] - mnew);
        float rsum = 0.f;
        #pragma unroll
        for (int n = 0; n < 4; ++n) {
            float p = __expf(vals[n] - mnew);
            rsum += p;
            int r = lhi * 4 + j;
            int off = ((r << 7) + ((n * 16 + l15) << 1)) ^ ((r & 7) << 4);
            *reinterpret_cast<bf16*>((char*)Plw + off) = (bf16)p;
        }
        #pragma unroll
        for (int ms = 1; ms < 16; ms <<= 1)
            rsum += __shfl_xor(rsum, ms, 16);
        l_i[j] = l_i[j] * cr + rsum;
        m_i[j] = mnew;
        corr[j] = cr;
    }

    #pragma unroll
    for (int n = 0; n < 8; ++n)
        #pragma unroll
        for (int j = 0; j < 4; ++j)
            o[n][j] *= corr[j];

    // PV (same-wave P: ordered by lgkmcnt, no barrier)
    #pragma unroll
    for (int kk = 0; kk < 2; ++kk) {
        bf16x8 pf = *reinterpret_cast<const bf16x8*>(
            (const char*)Plw + (l15 << 7) + ((((kk * 4 + lhi)) ^ (l15 & 7)) << 4));
        #pragma unroll
        for (int n = 0; n < 8; ++n) {
            int d = n * 16 + l15;
            bf16x8 vf = *reinterpret_cast<const bf16x8*>(
                (const char*)Vl + (d << 7) + ((((kk * 4 + lhi)) ^ (d & 7)) << 4));
            o[n] = __builtin_amdgcn_mfma_f32_16x16x32_bf16(pf, vf, o[n], 0, 0, 0);
        }
    }
}

__global__ __launch_bounds__(256) void flash_fwd2(
    const bf16* __restrict__ Q, const bf16* __restrict__ Kr,
    const bf16* __restrict__ VtG, bf16* __restrict__ ctx)
{
    __shared__ alignas(16) bf16 Kl[64 * 128];
    __shared__ alignas(16) bf16 Vl[128 * 64];
    __shared__ alignas(16) bf16 Pl[4][16 * 64];

    const int tid  = threadIdx.x;
    const int lane = tid & 63;
    const int wave = tid >> 6;
    const int l15 = lane & 15;
    const int lhi = lane >> 4;
    const int bid = blockIdx.x;
    const int qt = (NQT - 1) - (bid >> 5);   // longest tiles dispatched first
    const int h  = bid & 31;
    const int g  = h >> 2;
    const int q0 = qt * QBLK;

    bf16x8 qf[4];
    {
        const bf16* qp = Q + (size_t)(q0 + wave * 16 + l15) * HD + h * DH + lhi * 8;
        #pragma unroll
        for (int kk = 0; kk < 4; ++kk)
            qf[kk] = *reinterpret_cast<const bf16x8*>(qp + kk * 32);
    }

    f32x4 o[8] = {};
    float m_i[4] = { -1e30f, -1e30f, -1e30f, -1e30f };
    float l_i[4] = {};

    auto stage = [&](int t0) {
        #pragma unroll
        for (int t = 0; t < 4; ++t) {
            int ch = wave * 256 + t * 64 + lane;
            {   // K tile: row-major [64][128], 16 chunks/row
                int row = ch >> 4, ci = ch & 15;
                gload16(Kr + (size_t)(t0 + row) * GD + g * DH + ((ci ^ (row & 7)) << 3),
                        (char*)Kl + (wave * 256 + t * 64) * 16);
            }
            {   // V^T tile: [128][64], 8 chunks/row
                int d = ch >> 3, ci = ch & 7;
                gload16(VtG + (size_t)(g * DH + d) * S + t0 + ((ci ^ (d & 7)) << 3),
                        (char*)Vl + (wave * 256 + t * 64) * 16);
            }
        }
    };

    for (int t0 = 0; t0 < q0; t0 += KVBLK) {
        stage(t0);
        __syncthreads();
        attn_tile<false>(t0, q0, wave, l15, lhi, qf, Kl, Vl, &Pl[wave][0], o, m_i, l_i);
        __syncthreads();
    }
    stage(q0);
    __syncthreads();
    attn_tile<true>(q0, q0, wave, l15, lhi, qf, Kl, Vl, &Pl[wave][0], o, m_i, l_i);

    #pragma unroll
    for (int n = 0; n < 8; ++n) {
        int c = h * DH + n * 16 + l15;
        #pragma unroll
        for (int j = 0; j < 4; ++j) {
            int r = q0 + wave * 16 + lhi * 4 + j;
            ctx[(size_t)r * HD + c] = (bf16)(o[n][j] / l_i[j]);
        }
    }
}

// ---------------------------------------------------------------- launch
extern "C" void kernel_launch(void* const* d_in, const int* in_sizes, int n_in,
                              void* d_out, int out_size, void* d_ws, size_t ws_size,
                              hipStream_t stream)
{
    const float* x    = (const float*)d_in[0];
    const float* cosT = (const float*)d_in[2];
    const float* sinT = (const float*)d_in[3];
    const float* Wq   = (const float*)d_in[4];
    const float* Wk   = (const float*)d_in[5];
    const float* Wv   = (const float*)d_in[6];
    const float* Wo   = (const float*)d_in[7];
    float* out = (float*)d_out;

    const size_t MB = (size_t)1 << 20;
    char* ws = (char*)d_ws;
    bf16* xb  = (bf16*)ws;                         // 16MB
    bf16* ctx = (bf16*)(ws + 16 * MB);             // 16MB
    // d_out scratch (dead until final GEMM): Q 16MB | K 4MB | V 4MB | VtG 4MB
    bf16* Qb  = (bf16*)d_out;
    bf16* Kb  = Qb + (size_t)S * HD;
    bf16* Vb  = Kb + (size_t)S * GD;
    bf16* VtG = Vb + (size_t)S * GD;

    const bool fast = ws_size >= 112 * MB;
    const float qscale = 0.08838834764831845f;   // 1/sqrt(128), folded into Q RoPE

    cast_f32_bf16<<<(S * D / 4 + 255) / 256, 256, 0, stream>>>(x, xb, S * D / 4);

    if (fast) {
        bf16* Wqkvt = (bf16*)(ws + 32 * MB);       // [6144][4096] bf16 = 48MB
        bf16* Wot   = (bf16*)(ws + 80 * MB);       // [4096][4096] bf16 = 32MB

        transpose_to_bf16<true><<<dim3(HD / 512, D / 32), 256, 0, stream>>>(Wq, Wqkvt, D, HD);
        transpose_to_bf16<true><<<dim3(GD / 512, D / 32), 256, 0, stream>>>(Wk, Wqkvt + (size_t)HD * D, D, GD);
        transpose_to_bf16<true><<<dim3(GD / 512, D / 32), 256, 0, stream>>>(Wv, Wqkvt + (size_t)(HD + GD) * D, D, GD);
        transpose_to_bf16<true><<<dim3(D / 512, HD / 32), 256, 0, stream>>>(Wo, Wot, HD, D);

        gemm_bt<EPI_QKV><<<dim3((HD + 2 * GD) / BN, S / BM), 256, 0, stream>>>(
            xb, Wqkvt, (void*)Qb, Kb, Vb, S, HD + 2 * GD, D);

        rope_inplace<<<(S * HD / 2 + 255) / 256, 256, 0, stream>>>(Qb, cosT, sinT, HD, S * HD / 2, qscale);
        rope_inplace<<<(S * GD / 2 + 255) / 256, 256, 0, stream>>>(Kb, cosT, sinT, GD, S * GD / 2, 1.0f);

        transpose_to_bf16<false><<<dim3(GD / 512, S / 32), 256, 0, stream>>>(Vb, VtG, S, GD);

        flash_fwd2<<<NQT * H, 256, 0, stream>>>(Qb, Kb, VtG, ctx);

        gemm_bt<EPI_F32><<<dim3(D / BN, S / BM), 256, 0, stream>>>(
            ctx, Wot, (void*)out, nullptr, nullptr, S, D, HD);
    } else {
        gemm_aBf16<true><<<dim3(HD / BN, S / BM, 1), 256, 0, stream>>>(
            xb, Wq, Wq, (void*)Qb, (void*)Qb, S, HD, D);
        gemm_aBf16<true><<<dim3(GD / BN, S / BM, 2), 256, 0, stream>>>(
            xb, Wk, Wv, (void*)Kb, (void*)Vb, S, GD, D);

        rope_inplace<<<(S * HD / 2 + 255) / 256, 256, 0, stream>>>(Qb, cosT, sinT, HD, S * HD / 2, qscale);
        rope_inplace<<<(S * GD / 2 + 255) / 256, 256, 0, stream>>>(Kb, cosT, sinT, GD, S * GD / 2, 1.0f);

        transpose_to_bf16<false><<<dim3(GD / 512, S / 32), 256, 0, stream>>>(Vb, VtG, S, GD);

        flash_fwd2<<<NQT * H, 256, 0, stream>>>(Qb, Kb, VtG, ctx);

        gemm_aBf16<false><<<dim3(D / BN, S / BM, 1), 256, 0, stream>>>(
            ctx, Wo, Wo, (void*)out, (void*)out, S, D, HD);
    }

    (void)in_sizes; (void)n_in; (void)out_size; (void)ws_size;
}

// Round 3
// 389.642 us; speedup vs baseline: 1.4933x; 1.2669x over previous
//
#include <hip/hip_runtime.h>
#include <hip/hip_bf16.h>
#include <cstdint>
#include <cstddef>

#define S 2048
#define D 4096
#define H 32
#define G 8
#define DH 128
#define HD (H*DH)   // 4096
#define GD (G*DH)   // 1024

typedef __bf16 bf16;
typedef __bf16 bf16x4 __attribute__((ext_vector_type(4)));
typedef __bf16 bf16x8 __attribute__((ext_vector_type(8)));
typedef float f32x4 __attribute__((ext_vector_type(4)));

__device__ __forceinline__ void gload16(const void* g, void* l) {
    __builtin_amdgcn_global_load_lds(
        (const __attribute__((address_space(1))) void*)g,
        (__attribute__((address_space(3))) void*)l, 16, 0, 0);
}

#define FENCE() asm volatile("" ::: "memory")
#define BARRIER() do { FENCE(); __builtin_amdgcn_s_barrier(); FENCE(); } while (0)
#define LGKM0()  do { asm volatile("s_waitcnt lgkmcnt(0)" ::: "memory"); \
                      __builtin_amdgcn_sched_barrier(0); } while (0)

// ---------------------------------------------------------------- cast x -> bf16
__global__ __launch_bounds__(256) void cast_f32_bf16(const float* __restrict__ in,
                                                     bf16* __restrict__ out, int n4)
{
    int i = blockIdx.x * 256 + threadIdx.x;
    if (i < n4) {
        float4 v = reinterpret_cast<const float4*>(in)[i];
        bf16x4 o = { (bf16)v.x, (bf16)v.y, (bf16)v.z, (bf16)v.w };
        reinterpret_cast<bf16x4*>(out)[i] = o;
    }
}

// ---------------------------------------------------------------- transpose -> bf16
template<bool IN_F32>
__global__ __launch_bounds__(256) void transpose_to_bf16(
    const void* __restrict__ in, bf16* __restrict__ out, int R, int C)
{
    const int cb = threadIdx.x & 63, rb = threadIdx.x >> 6;
    const int c0 = blockIdx.x * 512 + cb * 8;
    const int r0 = blockIdx.y * 32 + rb * 8;
    bf16 m[8][8];
    #pragma unroll
    for (int j = 0; j < 8; ++j) {
        if constexpr (IN_F32) {
            const float* p = (const float*)in + (size_t)(r0 + j) * C + c0;
            float4 a = *reinterpret_cast<const float4*>(p);
            float4 b = *reinterpret_cast<const float4*>(p + 4);
            m[j][0] = (bf16)a.x; m[j][1] = (bf16)a.y; m[j][2] = (bf16)a.z; m[j][3] = (bf16)a.w;
            m[j][4] = (bf16)b.x; m[j][5] = (bf16)b.y; m[j][6] = (bf16)b.z; m[j][7] = (bf16)b.w;
        } else {
            const bf16* p = (const bf16*)in + (size_t)(r0 + j) * C + c0;
            bf16x8 v = *reinterpret_cast<const bf16x8*>(p);
            #pragma unroll
            for (int i = 0; i < 8; ++i) m[j][i] = v[i];
        }
    }
    #pragma unroll
    for (int i = 0; i < 8; ++i) {
        bf16x8 ov;
        #pragma unroll
        for (int j = 0; j < 8; ++j) ov[j] = m[j][i];
        *reinterpret_cast<bf16x8*>(out + (size_t)(c0 + i) * R + r0) = ov;
    }
}

// ---------------------------------------------------------------- RoPE in-place (+scale)
__global__ __launch_bounds__(256) void rope_inplace(bf16* __restrict__ Y,
                                                    const float* __restrict__ cosT,
                                                    const float* __restrict__ sinT,
                                                    int ncols, int total, float scale)
{
    int idx = blockIdx.x * 256 + threadIdx.x;
    if (idx >= total) return;
    int pairs = ncols >> 1;
    int s = idx / pairs;
    int p = idx - s * pairs;
    int head = p >> 6;
    int d = p & 63;
    size_t base = (size_t)s * ncols + head * DH;
    float c  = cosT[s * DH + d];
    float sn = sinT[s * DH + d];
    float a = (float)Y[base + d];
    float b = (float)Y[base + d + 64];
    Y[base + d]      = (bf16)((a * c - b * sn) * scale);
    Y[base + d + 64] = (bf16)((b * c + a * sn) * scale);
}

// ================================================================ pipelined GEMMs
// C[M,N] = A[M,K](bf16) * Bt[N,K](bf16).  Quad-buffered BK=32 K-pipeline:
// tile t+3 prefetched (global_load_lds, pre-swizzled source) while computing
// tile t; counted s_waitcnt vmcnt(N) placed BEFORE the phase-closing s_barrier
// so after the barrier ALL waves' loads for tile t+1 have landed. Raw
// s_barrier (no vmcnt drain). LDS chunk swizzle: chunk ^= (row>>1)&3 -> a
// wave's b128 column-read spreads uniformly over all 32 banks.

#define EPI_QKV 0
#define EPI_F32 1

// ---- 256x256 tile, 8 waves (2M x 4N), per-wave 128x64. LDS 128KB dynamic.
template<int EPI>
__global__ __launch_bounds__(512) void gemm_q(
    const bf16* __restrict__ A, const bf16* __restrict__ Bt,
    void* __restrict__ C, bf16* __restrict__ Kout, bf16* __restrict__ Vout,
    int N, int K, int nbn)
{
    extern __shared__ char smem[];          // A: 4 x 16KB | B: 4 x 16KB
    const int tid  = threadIdx.x;
    const int lane = tid & 63;
    const int wave = tid >> 6;
    const int wr = wave >> 2, wc = wave & 3;
    const int l15 = lane & 15, lhi = lane >> 4;

    const int nwg = gridDim.x;
    const int qq  = nwg >> 3;               // nwg % 8 == 0
    const int swz = (blockIdx.x & 7) * qq + (blockIdx.x >> 3);
    const int bm = (swz / nbn) * 256;
    const int bn = (swz % nbn) * 256;
    const int NT = K >> 5;

    size_t aoff[2], boff[2];
    int ldsoff[2];
    #pragma unroll
    for (int L = 0; L < 2; ++L) {
        int ci = L * 512 + tid;
        int row = ci >> 2, c = ci & 3, sw = (ci >> 3) & 3;
        aoff[L] = (size_t)(bm + row) * K + ((c ^ sw) << 3);
        boff[L] = (size_t)(bn + row) * K + ((c ^ sw) << 3);
        ldsoff[L] = (L * 512 + wave * 64) * 16;      // wave-uniform LDS base
    }

    auto stageA = [&](int t, int buf) {
        char* base = smem + buf * 16384;
        #pragma unroll
        for (int L = 0; L < 2; ++L)
            gload16(A + aoff[L] + t * 32, base + ldsoff[L]);
    };
    auto stageB = [&](int t, int buf) {
        char* base = smem + 65536 + buf * 16384;
        #pragma unroll
        for (int L = 0; L < 2; ++L)
            gload16(Bt + boff[L] + t * 32, base + ldsoff[L]);
    };

    const int swr   = (l15 >> 1) & 3;
    const int aBase = (wr * 128 + l15) * 64 + ((lhi ^ swr) << 4);
    const int bBase = (wc * 64  + l15) * 64 + ((lhi ^ swr) << 4);

    f32x4 acc[8][4] = {};

    stageA(0, 0); stageB(0, 0);
    stageA(1, 1); stageB(1, 1);
    stageA(2, 2); stageB(2, 2);
    asm volatile("s_waitcnt vmcnt(8)" ::: "memory");   // tile 0 landed (all waves)
    BARRIER();

    for (int t = 0; t < NT; ++t) {
        const int cur = t & 3;
        const int pf  = (t + 3 < NT) ? t + 3 : NT - 1;  // clamp: dummy loads hit dead buf
        const int pfb = (t + 3) & 3;
        const char* Ab = smem + cur * 16384;
        const char* Bb = smem + 65536 + cur * 16384;

        // ---------- phase A: quadrant m0-3
        bf16x8 bf[4], af[4];
        #pragma unroll
        for (int n = 0; n < 4; ++n)
            bf[n] = *reinterpret_cast<const bf16x8*>(Bb + bBase + n * 1024);
        #pragma unroll
        for (int m = 0; m < 4; ++m)
            af[m] = *reinterpret_cast<const bf16x8*>(Ab + aBase + m * 1024);
        stageA(pf, pfb);
        BARRIER();
        LGKM0();
        __builtin_amdgcn_s_setprio(1);
        #pragma unroll
        for (int m = 0; m < 4; ++m)
            #pragma unroll
            for (int n = 0; n < 4; ++n)
                acc[m][n] = __builtin_amdgcn_mfma_f32_16x16x32_bf16(af[m], bf[n], acc[m][n], 0, 0, 0);
        __builtin_amdgcn_s_setprio(0);
        BARRIER();

        // ---------- phase B: quadrant m4-7
        #pragma unroll
        for (int m = 0; m < 4; ++m)
            af[m] = *reinterpret_cast<const bf16x8*>(Ab + 4096 + aBase + m * 1024);
        stageB(pf, pfb);
        asm volatile("s_waitcnt vmcnt(8)" ::: "memory");  // tile t+1 landed; BEFORE barrier
        BARRIER();
        LGKM0();
        __builtin_amdgcn_s_setprio(1);
        #pragma unroll
        for (int m = 0; m < 4; ++m)
            #pragma unroll
            for (int n = 0; n < 4; ++n)
                acc[4 + m][n] = __builtin_amdgcn_mfma_f32_16x16x32_bf16(af[m], bf[n], acc[4 + m][n], 0, 0, 0);
        __builtin_amdgcn_s_setprio(0);
        BARRIER();
    }

    #pragma unroll
    for (int m = 0; m < 8; ++m) {
        int r0 = bm + wr * 128 + m * 16 + lhi * 4;
        #pragma unroll
        for (int n = 0; n < 4; ++n) {
            int c = bn + wc * 64 + n * 16 + l15;
            #pragma unroll
            for (int j = 0; j < 4; ++j) {
                if constexpr (EPI == EPI_F32) {
                    reinterpret_cast<float*>(C)[(size_t)(r0 + j) * N + c] = acc[m][n][j];
                } else {
                    if (bn < HD)
                        reinterpret_cast<bf16*>(C)[(size_t)(r0 + j) * HD + c] = (bf16)acc[m][n][j];
                    else if (bn < HD + GD)
                        Kout[(size_t)(r0 + j) * GD + (c - HD)] = (bf16)acc[m][n][j];
                    else
                        Vout[(size_t)(r0 + j) * GD + (c - HD - GD)] = (bf16)acc[m][n][j];
                }
            }
        }
    }
}

// ---- 256x128 tile, 8 waves (4M x 2N), per-wave 64x64. LDS 96KB dynamic. f32 out.
__global__ __launch_bounds__(512) void gemm_q128(
    const bf16* __restrict__ A, const bf16* __restrict__ Bt,
    float* __restrict__ C, int N, int K, int nbn)
{
    extern __shared__ char smem[];          // A: 4 x 16KB | B: 4 x 8KB
    const int tid  = threadIdx.x;
    const int lane = tid & 63;
    const int wave = tid >> 6;
    const int wr = wave >> 1, wc = wave & 1;
    const int l15 = lane & 15, lhi = lane >> 4;

    const int nwg = gridDim.x;
    const int qq  = nwg >> 3;
    const int swz = (blockIdx.x & 7) * qq + (blockIdx.x >> 3);
    const int bm = (swz / nbn) * 256;
    const int bn = (swz % nbn) * 128;
    const int NT = K >> 5;

    size_t aoff[2];
    int aldso[2];
    #pragma unroll
    for (int L = 0; L < 2; ++L) {
        int ci = L * 512 + tid;
        int row = ci >> 2, c = ci & 3, sw = (ci >> 3) & 3;
        aoff[L] = (size_t)(bm + row) * K + ((c ^ sw) << 3);
        aldso[L] = (L * 512 + wave * 64) * 16;
    }
    size_t boff;
    int bldso;
    {
        int ci = tid;
        int row = ci >> 2, c = ci & 3, sw = (ci >> 3) & 3;
        boff = (size_t)(bn + row) * K + ((c ^ sw) << 3);
        bldso = wave * 64 * 16;
    }

    auto stageA = [&](int t, int buf) {
        char* base = smem + buf * 16384;
        #pragma unroll
        for (int L = 0; L < 2; ++L)
            gload16(A + aoff[L] + t * 32, base + aldso[L]);
    };
    auto stageB = [&](int t, int buf) {
        gload16(Bt + boff + t * 32, smem + 65536 + buf * 8192 + bldso);
    };

    const int swr   = (l15 >> 1) & 3;
    const int aBase = (wr * 64 + l15) * 64 + ((lhi ^ swr) << 4);
    const int bBase = (wc * 64 + l15) * 64 + ((lhi ^ swr) << 4);

    f32x4 acc[4][4] = {};

    stageA(0, 0); stageB(0, 0);
    stageA(1, 1); stageB(1, 1);
    stageA(2, 2); stageB(2, 2);
    asm volatile("s_waitcnt vmcnt(6)" ::: "memory");
    BARRIER();

    for (int t = 0; t < NT; ++t) {
        const int cur = t & 3;
        const int pf  = (t + 3 < NT) ? t + 3 : NT - 1;
        const int pfb = (t + 3) & 3;
        const char* Ab = smem + cur * 16384;
        const char* Bb = smem + 65536 + cur * 8192;

        bf16x8 bf[4], af[4];
        #pragma unroll
        for (int n = 0; n < 4; ++n)
            bf[n] = *reinterpret_cast<const bf16x8*>(Bb + bBase + n * 1024);
        #pragma unroll
        for (int m = 0; m < 4; ++m)
            af[m] = *reinterpret_cast<const bf16x8*>(Ab + aBase + m * 1024);
        stageA(pf, pfb);
        stageB(pf, pfb);
        asm volatile("s_waitcnt vmcnt(6)" ::: "memory");  // tile t+1 landed; BEFORE barrier
        BARRIER();
        LGKM0();
        __builtin_amdgcn_s_setprio(1);
        #pragma unroll
        for (int m = 0; m < 4; ++m)
            #pragma unroll
            for (int n = 0; n < 4; ++n)
                acc[m][n] = __builtin_amdgcn_mfma_f32_16x16x32_bf16(af[m], bf[n], acc[m][n], 0, 0, 0);
        __builtin_amdgcn_s_setprio(0);
        BARRIER();
    }

    #pragma unroll
    for (int m = 0; m < 4; ++m) {
        int r0 = bm + wr * 64 + m * 16 + lhi * 4;
        #pragma unroll
        for (int n = 0; n < 4; ++n) {
            int c = bn + wc * 64 + n * 16 + l15;
            #pragma unroll
            for (int j = 0; j < 4; ++j)
                C[(size_t)(r0 + j) * N + c] = acc[m][n][j];
        }
    }
}

// ---------------------------------------------------------------- fallback GEMM (round-1)
#define BM 128
#define BN 128
#define BK 32
#define LDSK 40

template<bool OUT_BF16>
__global__ __launch_bounds__(256) void gemm_aBf16(
    const bf16* __restrict__ A,
    const float* __restrict__ B0, const float* __restrict__ B1,
    void* __restrict__ C0, void* __restrict__ C1,
    int M, int N, int K)
{
    __shared__ alignas(16) bf16 Al[BM][LDSK];
    __shared__ alignas(16) bf16 Bt[BN][LDSK];

    const float* __restrict__ B = blockIdx.z ? B1 : B0;
    void* __restrict__ C = blockIdx.z ? C1 : C0;

    const int tid  = threadIdx.x;
    const int lane = tid & 63;
    const int wave = tid >> 6;
    const int wm = (wave >> 1) * 64;
    const int wn = (wave & 1) * 64;
    const int bm = blockIdx.y * BM;
    const int bn = blockIdx.x * BN;
    const int l15 = lane & 15;
    const int lhi = lane >> 4;

    f32x4 acc[4][4] = {};

    for (int k0 = 0; k0 < K; k0 += BK) {
        #pragma unroll
        for (int it = 0; it < 2; ++it) {
            int idx = it * 256 + tid;
            int row = idx >> 2;
            int ko  = idx & 3;
            bf16x8 v = *reinterpret_cast<const bf16x8*>(
                A + (size_t)(bm + row) * K + k0 + ko * 8);
            *reinterpret_cast<bf16x8*>(&Al[row][ko * 8]) = v;
        }
        {
            int n = tid & 127;
            int kbase = (tid >> 7) * 8;
            const float* bp = B + (size_t)k0 * N + bn + n;
            #pragma unroll
            for (int half = 0; half < 2; ++half) {
                bf16x8 v;
                #pragma unroll
                for (int j = 0; j < 8; ++j)
                    v[j] = (bf16)bp[(size_t)(half * 16 + kbase + j) * N];
                *reinterpret_cast<bf16x8*>(&Bt[n][half * 16 + kbase]) = v;
            }
        }
        __syncthreads();

        bf16x8 af[4], bfv[4];
        #pragma unroll
        for (int m = 0; m < 4; ++m)
            af[m] = *reinterpret_cast<const bf16x8*>(&Al[wm + m * 16 + l15][lhi * 8]);
        #pragma unroll
        for (int n = 0; n < 4; ++n)
            bfv[n] = *reinterpret_cast<const bf16x8*>(&Bt[wn + n * 16 + l15][lhi * 8]);
        #pragma unroll
        for (int m = 0; m < 4; ++m)
            #pragma unroll
            for (int n = 0; n < 4; ++n)
                acc[m][n] = __builtin_amdgcn_mfma_f32_16x16x32_bf16(
                    af[m], bfv[n], acc[m][n], 0, 0, 0);
        __syncthreads();
    }

    #pragma unroll
    for (int m = 0; m < 4; ++m) {
        int r0 = bm + wm + m * 16 + lhi * 4;
        #pragma unroll
        for (int n = 0; n < 4; ++n) {
            int c = bn + wn + n * 16 + l15;
            #pragma unroll
            for (int j = 0; j < 4; ++j) {
                if constexpr (OUT_BF16)
                    reinterpret_cast<bf16*>(C)[(size_t)(r0 + j) * N + c] = (bf16)acc[m][n][j];
                else
                    reinterpret_cast<float*>(C)[(size_t)(r0 + j) * N + c] = acc[m][n][j];
            }
        }
    }
}

// ---------------------------------------------------------------- flash attention v2
#define QBLK 64
#define KVBLK 64
#define NQT (S/QBLK)

template<bool MASK>
__device__ __forceinline__ void attn_tile(
    int t0, int q0, int wave, int l15, int lhi,
    const bf16x8* qf, const bf16* Kl, const bf16* Vl, bf16* Plw,
    f32x4* o, float* m_i, float* l_i)
{
    f32x4 sc[4] = {};
    __builtin_amdgcn_s_setprio(1);
    #pragma unroll
    for (int n = 0; n < 4; ++n) {
        int row = n * 16 + l15;
        #pragma unroll
        for (int kk = 0; kk < 4; ++kk) {
            bf16x8 kf = *reinterpret_cast<const bf16x8*>(
                (const char*)Kl + row * 256 + ((((kk * 4 + lhi)) ^ (l15 & 7)) << 4));
            sc[n] = __builtin_amdgcn_mfma_f32_16x16x32_bf16(qf[kk], kf, sc[n], 0, 0, 0);
        }
    }
    __builtin_amdgcn_s_setprio(0);

    float corr[4];
    #pragma unroll
    for (int j = 0; j < 4; ++j) {
        const int qr = q0 + wave * 16 + lhi * 4 + j;
        float vals[4];
        float mx = -1e30f;
        #pragma unroll
        for (int n = 0; n < 4; ++n) {
            float v = sc[n][j];
            if constexpr (MASK) {
                int t = t0 + n * 16 + l15;
                if (t > qr) v = -1e30f;
            }
            vals[n] = v;
            mx = fmaxf(mx, v);
        }
        #pragma unroll
        for (int ms = 1; ms < 16; ms <<= 1)
            mx = fmaxf(mx, __shfl_xor(mx, ms, 16));
        float mnew = fmaxf(m_i[j], mx);
        float cr = __expf(m_i[j] - mnew);
        float rsum = 0.f;
        #pragma unroll
        for (int n = 0; n < 4; ++n) {
            float p = __expf(vals[n] - mnew);
            rsum += p;
            int r = lhi * 4 + j;
            int off = ((r << 7) + ((n * 16 + l15) << 1)) ^ ((r & 7) << 4);
            *reinterpret_cast<bf16*>((char*)Plw + off) = (bf16)p;
        }
        #pragma unroll
        for (int ms = 1; ms < 16; ms <<= 1)
            rsum += __shfl_xor(rsum, ms, 16);
        l_i[j] = l_i[j] * cr + rsum;
        m_i[j] = mnew;
        corr[j] = cr;
    }

    #pragma unroll
    for (int n = 0; n < 8; ++n)
        #pragma unroll
        for (int j = 0; j < 4; ++j)
            o[n][j] *= corr[j];

    __builtin_amdgcn_s_setprio(1);
    #pragma unroll
    for (int kk = 0; kk < 2; ++kk) {
        bf16x8 pf = *reinterpret_cast<const bf16x8*>(
            (const char*)Plw + (l15 << 7) + ((((kk * 4 + lhi)) ^ (l15 & 7)) << 4));
        #pragma unroll
        for (int n = 0; n < 8; ++n) {
            int d = n * 16 + l15;
            bf16x8 vf = *reinterpret_cast<const bf16x8*>(
                (const char*)Vl + (d << 7) + ((((kk * 4 + lhi)) ^ (d & 7)) << 4));
            o[n] = __builtin_amdgcn_mfma_f32_16x16x32_bf16(pf, vf, o[n], 0, 0, 0);
        }
    }
    __builtin_amdgcn_s_setprio(0);
}

__global__ __launch_bounds__(256) void flash_fwd2(
    const bf16* __restrict__ Q, const bf16* __restrict__ Kr,
    const bf16* __restrict__ VtG, bf16* __restrict__ ctx)
{
    __shared__ alignas(16) bf16 Kl[64 * 128];
    __shared__ alignas(16) bf16 Vl[128 * 64];
    __shared__ alignas(16) bf16 Pl[4][16 * 64];

    const int tid  = threadIdx.x;
    const int lane = tid & 63;
    const int wave = tid >> 6;
    const int l15 = lane & 15;
    const int lhi = lane >> 4;
    const int bid = blockIdx.x;
    const int qt = (NQT - 1) - (bid >> 5);
    const int h  = bid & 31;
    const int g  = h >> 2;
    const int q0 = qt * QBLK;

    bf16x8 qf[4];
    {
        const bf16* qp = Q + (size_t)(q0 + wave * 16 + l15) * HD + h * DH + lhi * 8;
        #pragma unroll
        for (int kk = 0; kk < 4; ++kk)
            qf[kk] = *reinterpret_cast<const bf16x8*>(qp + kk * 32);
    }

    f32x4 o[8] = {};
    float m_i[4] = { -1e30f, -1e30f, -1e30f, -1e30f };
    float l_i[4] = {};

    auto stage = [&](int t0) {
        #pragma unroll
        for (int t = 0; t < 4; ++t) {
            int ch = wave * 256 + t * 64 + lane;
            {
                int row = ch >> 4, ci = ch & 15;
                gload16(Kr + (size_t)(t0 + row) * GD + g * DH + ((ci ^ (row & 7)) << 3),
                        (char*)Kl + (wave * 256 + t * 64) * 16);
            }
            {
                int d = ch >> 3, ci = ch & 7;
                gload16(VtG + (size_t)(g * DH + d) * S + t0 + ((ci ^ (d & 7)) << 3),
                        (char*)Vl + (wave * 256 + t * 64) * 16);
            }
        }
    };

    for (int t0 = 0; t0 < q0; t0 += KVBLK) {
        stage(t0);
        __syncthreads();
        attn_tile<false>(t0, q0, wave, l15, lhi, qf, Kl, Vl, &Pl[wave][0], o, m_i, l_i);
        __syncthreads();
    }
    stage(q0);
    __syncthreads();
    attn_tile<true>(q0, q0, wave, l15, lhi, qf, Kl, Vl, &Pl[wave][0], o, m_i, l_i);

    #pragma unroll
    for (int n = 0; n < 8; ++n) {
        int c = h * DH + n * 16 + l15;
        #pragma unroll
        for (int j = 0; j < 4; ++j) {
            int r = q0 + wave * 16 + lhi * 4 + j;
            ctx[(size_t)r * HD + c] = (bf16)(o[n][j] / l_i[j]);
        }
    }
}

// ---------------------------------------------------------------- launch
extern "C" void kernel_launch(void* const* d_in, const int* in_sizes, int n_in,
                              void* d_out, int out_size, void* d_ws, size_t ws_size,
                              hipStream_t stream)
{
    const float* x    = (const float*)d_in[0];
    const float* cosT = (const float*)d_in[2];
    const float* sinT = (const float*)d_in[3];
    const float* Wq   = (const float*)d_in[4];
    const float* Wk   = (const float*)d_in[5];
    const float* Wv   = (const float*)d_in[6];
    const float* Wo   = (const float*)d_in[7];
    float* out = (float*)d_out;

    const size_t MB = (size_t)1 << 20;
    char* ws = (char*)d_ws;
    bf16* xb  = (bf16*)ws;                         // 16MB
    bf16* ctx = (bf16*)(ws + 16 * MB);             // 16MB
    bf16* Qb  = (bf16*)d_out;                      // d_out scratch (dead until final GEMM)
    bf16* Kb  = Qb + (size_t)S * HD;
    bf16* Vb  = Kb + (size_t)S * GD;
    bf16* VtG = Vb + (size_t)S * GD;

    const bool fast = ws_size >= 112 * MB;
    const float qscale = 0.08838834764831845f;

    cast_f32_bf16<<<(S * D / 4 + 255) / 256, 256, 0, stream>>>(x, xb, S * D / 4);

    if (fast) {
        bf16* Wqkvt = (bf16*)(ws + 32 * MB);       // [6144][4096] bf16 = 48MB
        bf16* Wot   = (bf16*)(ws + 80 * MB);       // [4096][4096] bf16 = 32MB

        transpose_to_bf16<true><<<dim3(HD / 512, D / 32), 256, 0, stream>>>(Wq, Wqkvt, D, HD);
        transpose_to_bf16<true><<<dim3(GD / 512, D / 32), 256, 0, stream>>>(Wk, Wqkvt + (size_t)HD * D, D, GD);
        transpose_to_bf16<true><<<dim3(GD / 512, D / 32), 256, 0, stream>>>(Wv, Wqkvt + (size_t)(HD + GD) * D, D, GD);
        transpose_to_bf16<true><<<dim3(D / 512, HD / 32), 256, 0, stream>>>(Wo, Wot, HD, D);

        hipFuncSetAttribute(reinterpret_cast<const void*>(&gemm_q<EPI_QKV>),
                            hipFuncAttributeMaxDynamicSharedMemorySize, 131072);
        hipFuncSetAttribute(reinterpret_cast<const void*>(&gemm_q128),
                            hipFuncAttributeMaxDynamicSharedMemorySize, 98304);

        // QKV: M=2048, N=6144, K=4096 -> 8x24 = 192 blocks
        gemm_q<EPI_QKV><<<192, 512, 131072, stream>>>(
            xb, Wqkvt, (void*)Qb, Kb, Vb, HD + 2 * GD, D, 24);

        rope_inplace<<<(S * HD / 2 + 255) / 256, 256, 0, stream>>>(Qb, cosT, sinT, HD, S * HD / 2, qscale);
        rope_inplace<<<(S * GD / 2 + 255) / 256, 256, 0, stream>>>(Kb, cosT, sinT, GD, S * GD / 2, 1.0f);

        transpose_to_bf16<false><<<dim3(GD / 512, S / 32), 256, 0, stream>>>(Vb, VtG, S, GD);

        flash_fwd2<<<NQT * H, 256, 0, stream>>>(Qb, Kb, VtG, ctx);

        // Wo: M=2048, N=4096, K=4096 -> 8x32 = 256 blocks (256x128 tile)
        gemm_q128<<<256, 512, 98304, stream>>>(ctx, Wot, out, D, HD, 32);
    } else {
        gemm_aBf16<true><<<dim3(HD / BN, S / BM, 1), 256, 0, stream>>>(
            xb, Wq, Wq, (void*)Qb, (void*)Qb, S, HD, D);
        gemm_aBf16<true><<<dim3(GD / BN, S / BM, 2), 256, 0, stream>>>(
            xb, Wk, Wv, (void*)Kb, (void*)Vb, S, GD, D);

        rope_inplace<<<(S * HD / 2 + 255) / 256, 256, 0, stream>>>(Qb, cosT, sinT, HD, S * HD / 2, qscale);
        rope_inplace<<<(S * GD / 2 + 255) / 256, 256, 0, stream>>>(Kb, cosT, sinT, GD, S * GD / 2, 1.0f);

        transpose_to_bf16<false><<<dim3(GD / 512, S / 32), 256, 0, stream>>>(Vb, VtG, S, GD);

        flash_fwd2<<<NQT * H, 256, 0, stream>>>(Qb, Kb, VtG, ctx);

        gemm_aBf16<false><<<dim3(D / BN, S / BM, 1), 256, 0, stream>>>(
            ctx, Wo, Wo, (void*)out, (void*)out, S, D, HD);
    }

    (void)in_sizes; (void)n_in; (void)out_size; (void)ws_size;
}